// Round 18
// baseline (590.027 us; speedup 1.0000x reference)
//
#include <hip/hip_runtime.h>

typedef unsigned short u16;
typedef __attribute__((ext_vector_type(8))) short short8;
typedef __attribute__((ext_vector_type(4))) float f32x4;

#define AS1 __attribute__((address_space(1)))
#define AS3 __attribute__((address_space(3)))

__device__ __forceinline__ void async_cp16(const void* g, void* l) {
  __builtin_amdgcn_global_load_lds((const AS1 unsigned int*)g, (AS3 unsigned int*)l, 16, 0, 0);
}

__device__ __forceinline__ u16 f2bf(float f) {
  union { float f; unsigned u; } v; v.f = f;
  unsigned r = v.u + 0x7fffu + ((v.u >> 16) & 1u);
  return (u16)(r >> 16);
}
__device__ __forceinline__ float bf2f(u16 h) {
  union { unsigned u; float f; } v; v.u = ((unsigned)h) << 16;
  return v.f;
}

// ---------------------------------------------------------------------------
// Big diffusion GEMM — R18: R14/R17 8-phase pipeline (580-583us total,
// gemm32 152-154us, MfmaUtil 37.5%) with TEMPLATE-EXACT phase interiors:
// {reads | stage -> [lgkm(8) hint if 12 reads] -> barrier -> lgkmcnt(0) ->
//  setprio + 16 MFMA + setprio -> barrier}. The first barrier releases all
// waves' ds_reads into the LDS queue together and makes the MFMA region
// pure-register (T5's role-split precondition; m201 measures 62% MfmaUtil
// on this geometry with this interior). Boundary vmcnt(4) unchanged at
// ph3/ph7 after MFMA (ledger: retires tile T+1's A+B, leaves B(T+2) in
// flight; never drain-0 mid-loop). All else identical to R17.
// 256x256 tile, BK=64, 8 waves (2Mx4N), 16x16x32 MFMA, acc[8][4], snake
// (0,0)(0,1)(1,1)(1,0), per-phase reads 12/4/8/0. LDS 128KB = 2 dbuf x
// {A,B} x 2 halves x 2 K-panels [128][32] u16 (64B stride, 2-bit XOR).
// Pair-fused: by>>3 selects attn vs prior path.
// MODE 1: packed Crow + transposed Ct;  MODE 2: packed Crow only.
// ---------------------------------------------------------------------------
template<int MODE>
__global__ __launch_bounds__(512, 2) void gemm32(
    const u16* __restrict__ Aa, const u16* __restrict__ Ap,
    const u16* __restrict__ Ba, const u16* __restrict__ Bp,
    int N, int K,
    u16* __restrict__ Crow, int crow_ld,
    u16* __restrict__ Cta, u16* __restrict__ Ctp, int ct_ld)
{
  extern __shared__ u16 smem[];   // 65536 u16 = 128KB
  const int tid  = threadIdx.x;
  const int lane = tid & 63;
  const int w    = tid >> 6;             // 0..7
  const int half2 = blockIdx.y >> 3;     // 0: attn-path, 1: prior-path
  const int m0 = (blockIdx.y & 7) * 256;
  const int n0 = blockIdx.x * 256;
  const u16* A = half2 ? Ap : Aa;
  const u16* B = half2 ? Bp : Ba;
  const int coloff = half2 * 128;
  const int wm2 = w >> 2;                // 0..1 : M rows wm2*128..+127
  const int wn4 = w & 3;                 // 0..3 : N cols wn4*64..+63
  const int nh  = wn4 >> 1;              // B half
  const int nsub = (wn4 & 1) * 64;       // row base within B half
  const int ml = lane & 15;
  const int qd = lane >> 4;
  const int qs = (qd ^ ((ml >> 1) & 3)) * 8;   // swizzled read chunk (u16)

  f32x4 acc[8][4];
  const f32x4 zero = {0.f, 0.f, 0.f, 0.f};
#pragma unroll
  for (int i = 0; i < 8; i++)
#pragma unroll
    for (int j = 0; j < 4; j++) acc[i][j] = zero;

  const int sr  = lane >> 2;
  const int gch = ((lane & 3) ^ ((lane >> 3) & 3)) * 8;

#define ST_A(tt, hh) do {                                                     \
    u16* d0_ = smem + ((tt) & 1) * 32768 + ((hh) * 2 + 0) * 4096 + w * 512;   \
    u16* d1_ = smem + ((tt) & 1) * 32768 + ((hh) * 2 + 1) * 4096 + w * 512;   \
    const u16* s_ = A + (size_t)(m0 + (hh) * 128 + w * 16 + sr) * K + (tt) * 64 + gch; \
    async_cp16(s_, d0_); async_cp16(s_ + 32, d1_);                            \
  } while (0)
#define ST_B(tt, hhn) do {                                                    \
    u16* d0_ = smem + ((tt) & 1) * 32768 + 16384 + ((hhn) * 2 + 0) * 4096 + w * 512; \
    u16* d1_ = smem + ((tt) & 1) * 32768 + 16384 + ((hhn) * 2 + 1) * 4096 + w * 512; \
    const u16* s_ = B + (size_t)(n0 + (hhn) * 128 + w * 16 + sr) * K + (tt) * 64 + gch; \
    async_cp16(s_, d0_); async_cp16(s_ + 32, d1_);                            \
  } while (0)

  short8 Af[4][2], Bf[2][2][2];   // Af[i][ks]; Bf[nq][jf][ks]

#define READA(dbase, mq) do {                                                 \
    _Pragma("unroll")                                                         \
    for (int i_ = 0; i_ < 4; i_++)                                            \
      _Pragma("unroll")                                                       \
      for (int ks_ = 0; ks_ < 2; ks_++)                                       \
        Af[i_][ks_] = *(const short8*)(smem + (dbase) + (wm2 * 2 + ks_) * 4096 \
            + ((mq) * 64 + i_ * 16 + ml) * 32 + qs);                          \
  } while (0)
#define READB(dbase, nq) do {                                                 \
    _Pragma("unroll")                                                         \
    for (int jf_ = 0; jf_ < 2; jf_++)                                         \
      _Pragma("unroll")                                                       \
      for (int ks_ = 0; ks_ < 2; ks_++)                                       \
        Bf[nq][jf_][ks_] = *(const short8*)(smem + (dbase) + 16384            \
            + (nh * 2 + ks_) * 4096 + (nsub + (nq) * 32 + jf_ * 16 + ml) * 32 + qs); \
  } while (0)
#define MFMAQ(mq, nq) do {                                                    \
    __builtin_amdgcn_s_setprio(1);                                            \
    _Pragma("unroll")                                                         \
    for (int i_ = 0; i_ < 4; i_++)                                            \
      _Pragma("unroll")                                                       \
      for (int jf_ = 0; jf_ < 2; jf_++)                                       \
        _Pragma("unroll")                                                     \
        for (int ks_ = 0; ks_ < 2; ks_++)                                     \
          acc[(mq) * 4 + i_][(nq) * 2 + jf_] = __builtin_amdgcn_mfma_f32_16x16x32_bf16( \
              Af[i_][ks_], Bf[nq][jf_][ks_], acc[(mq) * 4 + i_][(nq) * 2 + jf_], 0, 0, 0); \
    __builtin_amdgcn_s_setprio(0);                                            \
  } while (0)
  // template-exact phase tail: pre-MFMA barrier + lgkm(0); MFMA; close barrier
#define PH_SPLIT() do {                                                       \
    __builtin_amdgcn_s_barrier();                                             \
    asm volatile("s_waitcnt lgkmcnt(0)" ::: "memory");                        \
    __builtin_amdgcn_sched_barrier(0);                                        \
  } while (0)

  const int NTI = K >> 7;                // iterations; 2 K-tiles each
  ST_B(0, 0); ST_B(0, 1); ST_A(0, 0); ST_A(0, 1); ST_B(1, 0); ST_B(1, 1);
  asm volatile("s_waitcnt vmcnt(4)" ::: "memory");
  __builtin_amdgcn_s_barrier();

  for (int j = 0; j < NTI; ++j) {
    const int T = 2 * j;
    const bool st = (j + 1 < NTI);
    const int b0 = 0;
    const int b1 = 32768;

    // ---- ph0: T (0,0); stage A0(T+1); 12 reads -> lgkm(8) hint
    READA(b0, 0); READB(b0, 0);
    ST_A(T + 1, 0);
    asm volatile("s_waitcnt lgkmcnt(8)" ::: "memory");
    PH_SPLIT();
    MFMAQ(0, 0);
    __builtin_amdgcn_s_barrier();
    // ---- ph1: T (0,1); stage A1(T+1)
    READB(b0, 1);
    ST_A(T + 1, 1);
    PH_SPLIT();
    MFMAQ(0, 1);
    __builtin_amdgcn_s_barrier();
    // ---- ph2: T (1,1); stage B0(T+2)
    READA(b0, 1);
    if (st) ST_B(T + 2, 0);
    PH_SPLIT();
    MFMAQ(1, 1);
    __builtin_amdgcn_s_barrier();
    // ---- ph3: T (1,0); stage B1(T+2); boundary wait (counted)
    if (st) ST_B(T + 2, 1);
    PH_SPLIT();
    MFMAQ(1, 0);
    if (st) { asm volatile("s_waitcnt vmcnt(4)" ::: "memory"); }
    else    { asm volatile("s_waitcnt vmcnt(0)" ::: "memory"); }
    __builtin_amdgcn_s_barrier();
    // ---- ph4: T+1 (0,0); stage A0(T+2); 12 reads -> lgkm(8) hint
    READA(b1, 0); READB(b1, 0);
    if (st) ST_A(T + 2, 0);
    asm volatile("s_waitcnt lgkmcnt(8)" ::: "memory");
    PH_SPLIT();
    MFMAQ(0, 0);
    __builtin_amdgcn_s_barrier();
    // ---- ph5: T+1 (0,1); stage A1(T+2)
    READB(b1, 1);
    if (st) ST_A(T + 2, 1);
    PH_SPLIT();
    MFMAQ(0, 1);
    __builtin_amdgcn_s_barrier();
    // ---- ph6: T+1 (1,1); stage B0(T+3)
    READA(b1, 1);
    if (st) ST_B(T + 3, 0);
    PH_SPLIT();
    MFMAQ(1, 1);
    __builtin_amdgcn_s_barrier();
    // ---- ph7: T+1 (1,0); stage B1(T+3); boundary wait
    if (st) ST_B(T + 3, 1);
    PH_SPLIT();
    MFMAQ(1, 0);
    if (st) { asm volatile("s_waitcnt vmcnt(4)" ::: "memory"); }
    else    { asm volatile("s_waitcnt vmcnt(0)" ::: "memory"); }
    __builtin_amdgcn_s_barrier();
  }
#undef ST_A
#undef ST_B
#undef READA
#undef READB
#undef MFMAQ
#undef PH_SPLIT

  // Epilogues. C/D (m89): M-row = base + qd*4 + r, N-col = base + ml.
  u16* T = smem;   // [64][264] bounce (loop exited via barrier, all LDS dead)

  // packed row-major: 4 passes of 64 M-rows
#pragma unroll
  for (int pr = 0; pr < 4; pr++) {
    if (wm2 == (pr >> 1)) {
      const int mq = pr & 1;
#pragma unroll
      for (int i = 0; i < 4; i++)
#pragma unroll
        for (int nj = 0; nj < 4; nj++)
#pragma unroll
          for (int r = 0; r < 4; r++)
            T[(i * 16 + qd * 4 + r) * 264 + wn4 * 64 + nj * 16 + ml] =
                f2bf(acc[mq * 4 + i][nj][r]);
    }
    __syncthreads();
    {
      const int row = tid >> 3, c8 = tid & 7;    // 64 rows x 8 chunks of 32 u16
      const size_t grow = (size_t)(m0 + pr * 64 + row);
      const size_t crow = grow * (size_t)(N >> 7) + (n0 >> 7) + (c8 >> 2);
      u16* dst = Crow + crow * (size_t)crow_ld + coloff + (c8 & 3) * 32;
      const u16* src = T + row * 264 + c8 * 32;
#pragma unroll
      for (int u = 0; u < 4; u++) ((float4*)dst)[u] = ((const float4*)src)[u];
    }
    __syncthreads();
  }

  if constexpr (MODE == 1) {
    u16* Ct = half2 ? Ctp : Cta;
    // transposed: Ct[n][m], 4 passes of 64 n-rows x 256 m-cols
#pragma unroll
    for (int p = 0; p < 4; p++) {
      if (wn4 == p) {
#pragma unroll
        for (int mi = 0; mi < 8; mi++)
#pragma unroll
          for (int nj = 0; nj < 4; nj++)
#pragma unroll
            for (int r = 0; r < 4; r++) {
              const int nloc = nj * 16 + ml;
              const int mcol = wm2 * 128 + (mi >> 2) * 64 + (mi & 3) * 16 + qd * 4 + r;
              T[nloc * 264 + mcol] = f2bf(acc[mi][nj][r]);
            }
      }
      __syncthreads();
      {
        const int row = tid >> 3, c8 = tid & 7;
        u16* dst = Ct + (size_t)(n0 + p * 64 + row) * ct_ld + m0 + c8 * 32;
        const u16* src = T + row * 264 + c8 * 32;
#pragma unroll
        for (int u = 0; u < 4; u++) ((float4*)dst)[u] = ((const float4*)src)[u];
      }
      __syncthreads();
    }
  }
}

// ---------------------------------------------------------------------------
// 16x16x32 GEMM (small shapes) — R14 BK=32 body (583us config). R9 chunk-XOR
// swizzle: store chunk c of row r at c ^ ((r>>1)&3); read qd ^ ((ml>>1)&3).
// MODE 2: bf16 packed row-major; MODE 3: f32 plain.
// ---------------------------------------------------------------------------
template<int MODE>
__global__ __launch_bounds__(256) void gemm_bt(
    const u16* __restrict__ A, const u16* __restrict__ B,
    int M, int N, int K,
    float* __restrict__ Cf,
    u16* __restrict__ Crow, int crow_ld, int crow_coloff)
{
  extern __shared__ char smemc[];
  u16* sA = (u16*)smemc;
  u16* sB = (u16*)(smemc + 8192);
  const int tid  = threadIdx.x;
  const int lane = tid & 63;
  const int wid  = tid >> 6;
  const int m0 = blockIdx.y * 128;
  const int n0 = blockIdx.x * 128;
  const int wm = (wid >> 1) * 64;
  const int wn = (wid & 1) * 64;
  const int ml = lane & 15;
  const int qd = lane >> 4;
  const int qs = (qd ^ ((ml >> 1) & 3)) * 8;   // swizzled read chunk (u16)

  f32x4 acc[4][4];
  const f32x4 zero = {0.f, 0.f, 0.f, 0.f};
#pragma unroll
  for (int i = 0; i < 4; i++)
#pragma unroll
    for (int j = 0; j < 4; j++) acc[i][j] = zero;

  const int r4 = tid >> 2;
  const int pq = (r4 >> 1) & 3;                // staging row swizzle key
  const int c4 = ((tid & 3) ^ pq) * 8;         // swizzled global source chunk
  const u16* gA0 = A + (size_t)(m0 + r4) * K + c4;
  const u16* gA1 = A + (size_t)(m0 + 64 + r4) * K + c4;
  const u16* gB0 = B + (size_t)(n0 + r4) * K + c4;
  const u16* gB1 = B + (size_t)(n0 + 64 + r4) * K + c4;
  u16* lA0 = sA + wid * 512;
  u16* lA1 = sA + 2048 + wid * 512;
  u16* lB0 = sB + wid * 512;
  u16* lB1 = sB + 2048 + wid * 512;

  for (int k0 = 0; k0 < K; k0 += 32) {
    async_cp16(gA0 + k0, lA0);
    async_cp16(gA1 + k0, lA1);
    async_cp16(gB0 + k0, lB0);
    async_cp16(gB1 + k0, lB1);
    __syncthreads();
    short8 af[4], bfr[4];
#pragma unroll
    for (int i = 0; i < 4; i++)
      af[i] = *(const short8*)(sA + (wm + i * 16 + ml) * 32 + qs);
#pragma unroll
    for (int j = 0; j < 4; j++)
      bfr[j] = *(const short8*)(sB + (wn + j * 16 + ml) * 32 + qs);
#pragma unroll
    for (int i = 0; i < 4; i++)
#pragma unroll
      for (int j = 0; j < 4; j++)
        acc[i][j] = __builtin_amdgcn_mfma_f32_16x16x32_bf16(af[i], bfr[j], acc[i][j], 0, 0, 0);
    __syncthreads();
  }

  if constexpr (MODE == 3) {
#pragma unroll
    for (int i = 0; i < 4; i++) {
      const int mr = m0 + wm + i * 16 + qd * 4;
#pragma unroll
      for (int j = 0; j < 4; j++) {
        const int nc = n0 + wn + j * 16 + ml;
        float* p = Cf + (size_t)mr * N + nc;
#pragma unroll
        for (int r = 0; r < 4; r++) p[(size_t)r * N] = acc[i][j][r];
      }
    }
  } else {
    u16* T = (u16*)smemc;  // [128][136]
#pragma unroll
    for (int i = 0; i < 4; i++)
#pragma unroll
      for (int j = 0; j < 4; j++)
#pragma unroll
        for (int r = 0; r < 4; r++)
          T[(wm + i * 16 + qd * 4 + r) * 136 + wn + j * 16 + ml] = f2bf(acc[i][j][r]);
    __syncthreads();
    const int row = tid >> 1, halfr = tid & 1;
    const size_t crow = (size_t)(m0 + row) * (N >> 7) + (n0 >> 7);
    u16* dst = Crow + crow * (size_t)crow_ld + crow_coloff + halfr * 64;
    const u16* src = T + row * 136 + halfr * 64;
#pragma unroll
    for (int u = 0; u < 8; u++) ((float4*)dst)[u] = ((const float4*)src)[u];
  }
}

// ---------------------------------------------------------------------------
// prep_k: merged prologue (one dispatch, block-range branch):
//  [0,2048) priornorm | [2048,6144) convx | [6144,6400) convw
// ---------------------------------------------------------------------------
__global__ __launch_bounds__(256) void prep_k(
    const float* __restrict__ prior, ushort4* __restrict__ priorS,
    const float* __restrict__ x, u16* __restrict__ xt,
    const float* __restrict__ pw, const float* __restrict__ aw,
    u16* __restrict__ btc)
{
  const int bid = blockIdx.x;
  const int t = threadIdx.x;
  if (bid < 2048) {
    __shared__ float red[256];
    const int i = bid;
    const float* p = prior + (size_t)i * 2048;
    float s = 0.f;
    for (int j = t; j < 2048; j += 256) s += p[j];
    red[t] = s; __syncthreads();
    for (int o = 128; o; o >>= 1) { if (t < o) red[t] += red[t + o]; __syncthreads(); }
    const float inv = 1.0f / red[0];
    const float4* pv = (const float4*)p;
    ushort4* dv = priorS + (size_t)i * 512;
#pragma unroll
    for (int j = t; j < 512; j += 256) {
      const float4 v = pv[j];
      ushort4 o;
      o.x = f2bf(v.x * inv); o.y = f2bf(v.y * inv); o.z = f2bf(v.z * inv); o.w = f2bf(v.w * inv);
      dv[j] = o;
    }
  } else if (bid < 6144) {
    __shared__ float S[64][65];
    const int b2 = bid - 2048;
    const int n0 = (b2 & 127) * 64;
    const int j0 = (b2 >> 7) * 64;
    const int rr = t >> 4, cxc = (t & 15) * 4;
#pragma unroll
    for (int p = 0; p < 4; p++) {
      const float4 v = *(const float4*)(x + (size_t)(j0 + rr + p * 16) * 8192 + n0 + cxc);
      S[rr + p * 16][cxc + 0] = v.x; S[rr + p * 16][cxc + 1] = v.y;
      S[rr + p * 16][cxc + 2] = v.z; S[rr + p * 16][cxc + 3] = v.w;
    }
    __syncthreads();
    const int nl = t >> 2, ch = (t & 3) * 16;
    alignas(16) u16 tmp[16];
#pragma unroll
    for (int u = 0; u < 16; u++) tmp[u] = f2bf(S[ch + u][nl]);
    float4* dst = (float4*)(xt + (size_t)(n0 + nl) * 2048 + j0 + ch);
    dst[0] = ((const float4*)tmp)[0];
    dst[1] = ((const float4*)tmp)[1];
  } else {
    const int idx = (bid - 6144) * 256 + t;
    const int k = idx & 255, d = (idx >> 8) & 127, s = idx >> 15;
    const float v = (k < 128) ? aw[(s * 128 + d) * 128 + k] : pw[(s * 128 + d) * 128 + (k - 128)];
    btc[idx] = f2bf(v);
  }
}

// ---------------------------------------------------------------------------
// pooled_epre_k<SRC>: fused pooled + epre
// ---------------------------------------------------------------------------
template<int SRC>
__global__ __launch_bounds__(256) void pooled_epre_k(
    const float* __restrict__ xf, const u16* __restrict__ comb,
    const float* __restrict__ W1, const float* __restrict__ W2,
    const float* __restrict__ W3,
    u16* __restrict__ e3b, u16* __restrict__ fb)
{
  __shared__ float red[256];
  __shared__ float pr[128];
  __shared__ float e1s[64];
  const int i = blockIdx.x, t = threadIdx.x;
  const int c = t & 127, h = t >> 7;
  float s = 0.f;
  if constexpr (SRC == 0) {
    const float* base = xf + (size_t)i * 8192 + c;
    for (int k = h * 32; k < h * 32 + 32; k++) s += base[(size_t)k * 128];
  } else {
    const u16* base = comb + (size_t)i * 64 * 256 + c;
    for (int k = h * 32; k < h * 32 + 32; k++) s += bf2f(base[(size_t)k * 256]);
  }
  red[t] = s; __syncthreads();
  if (t < 128) pr[t] = (red[t] + red[t + 128]) * (1.f / 64.f);
  __syncthreads();
  if (t < 128) {
    const float* Wm = (t < 64) ? W1 : W3;
    const int d = t & 63;
    float sv = 0.f;
    for (int cc = 0; cc < 128; cc++) sv += pr[cc] * Wm[d * 128 + cc];
    if (t < 64) e1s[d] = sv;
    else        e3b[i * 64 + d] = f2bf(sv);
  }
  __syncthreads();
  if (t < 64) {
    float sf = 0.f;
    for (int dd = 0; dd < 64; dd++) sf += e1s[dd] * W2[t * 64 + dd];
    fb[i * 64 + t] = f2bf(sf);
  }
}

__device__ __forceinline__ float waveRedSum(float v) {
#pragma unroll
  for (int o = 1; o < 64; o <<= 1) v += __shfl_xor(v, o);
  return __shfl(v, 0);
}
__device__ __forceinline__ float waveRedMax(float v) {
#pragma unroll
  for (int o = 1; o < 64; o <<= 1) v = fmaxf(v, __shfl_xor(v, o));
  return __shfl(v, 0);
}

__global__ __launch_bounds__(256) void topp_k(const float* __restrict__ logits,
                                              u16* __restrict__ attnb) {
  const int w = threadIdx.x >> 6, l = threadIdx.x & 63;
  const int i = blockIdx.x * 4 + w;
  const float4* row = (const float4*)(logits + (size_t)i * 2048);
  float E[32];
  float mx = -1e30f;
#pragma unroll
  for (int k = 0; k < 8; k++) {
    const float4 v = row[k * 64 + l];
    E[k * 4 + 0] = v.x; E[k * 4 + 1] = v.y; E[k * 4 + 2] = v.z; E[k * 4 + 3] = v.w;
    mx = fmaxf(fmaxf(mx, fmaxf(v.x, v.y)), fmaxf(v.z, v.w));
  }
  mx = waveRedMax(mx);
  float S = 0.f;
#pragma unroll
  for (int u = 0; u < 32; u++) { E[u] = __expf(E[u] - mx); S += E[u]; }
  S = waveRedSum(S);
  const float target = 0.9f * S;
  float lo = 0.f, hi = 1.f;
  for (int it = 0; it < 32; ++it) {
    const float mid = 0.5f * (lo + hi);
    float g = 0.f;
#pragma unroll
    for (int u = 0; u < 32; u++) g += (E[u] > mid) ? E[u] : 0.f;
    g = waveRedSum(g);
    const bool below = (g < target);
    hi = below ? mid : hi;
    lo = below ? lo : mid;
  }
  float Sk = 0.f;
#pragma unroll
  for (int u = 0; u < 32; u++) Sk += (E[u] > lo) ? E[u] : 0.f;
  Sk = waveRedSum(Sk);
  const float inv = 1.f / Sk;
  u16* dst = attnb + (size_t)i * 2048;
#pragma unroll
  for (int k = 0; k < 8; k++) {
    ushort4 o;
    o.x = f2bf(E[k * 4 + 0] > lo ? E[k * 4 + 0] * inv : 0.f);
    o.y = f2bf(E[k * 4 + 1] > lo ? E[k * 4 + 1] * inv : 0.f);
    o.z = f2bf(E[k * 4 + 2] > lo ? E[k * 4 + 2] * inv : 0.f);
    o.w = f2bf(E[k * 4 + 3] > lo ? E[k * 4 + 3] * inv : 0.f);
    *(ushort4*)(dst + k * 256 + l * 4) = o;
  }
}

// out = LN(x + gate*(d1+d2))*gamma + beta  (deltas stored bf16)
__global__ void ln_k(const float* __restrict__ x,
                     const u16* __restrict__ d1, const u16* __restrict__ d2,
                     float* __restrict__ out,
                     const float* __restrict__ gamma, const float* __restrict__ beta,
                     const float* __restrict__ alpha) {
  const int wid = threadIdx.x >> 6, lane = threadIdx.x & 63;
  const float gate = 1.f / (1.f + expf(-alpha[0]));
  const float2 g = ((const float2*)gamma)[lane];
  const float2 b = ((const float2*)beta)[lane];
#pragma unroll
  for (int rr = 0; rr < 2; ++rr) {
    const size_t row = (size_t)blockIdx.x * 8 + wid * 2 + rr;
    const float2 xv = ((const float2*)(x + row * 128))[lane];
    const ushort2 r1 = ((const ushort2*)(d1 + row * 128))[lane];
    const ushort2 r2 = ((const ushort2*)(d2 + row * 128))[lane];
    const float h0 = xv.x + gate * (bf2f(r1.x) + bf2f(r2.x));
    const float h1 = xv.y + gate * (bf2f(r1.y) + bf2f(r2.y));
    float s = h0 + h1;
#pragma unroll
    for (int o = 32; o; o >>= 1) s += __shfl_down(s, o);
    const float mu = __shfl(s, 0) * (1.f / 128.f);
    const float d0 = h0 - mu, dd1 = h1 - mu;
    float vs = d0 * d0 + dd1 * dd1;
#pragma unroll
    for (int o = 32; o; o >>= 1) vs += __shfl_down(vs, o);
    const float rstd = rsqrtf(__shfl(vs, 0) * (1.f / 128.f) + 1e-5f);
    float2* op = (float2*)(out + row * 128);
    float2 ov;
    ov.x = d0 * rstd * g.x + b.x;
    ov.y = dd1 * rstd * g.y + b.y;
    op[lane] = ov;
  }
}

// ---------------------------------------------------------------------------
extern "C" void kernel_launch(void* const* d_in, const int* in_sizes, int n_in,
                              void* d_out, int out_size, void* d_ws, size_t ws_size,
                              hipStream_t stream) {
  const float* x     = (const float*)d_in[0];
  const float* prior = (const float*)d_in[1];
  const float* W1    = (const float*)d_in[2];
  const float* W2    = (const float*)d_in[3];
  const float* W3    = (const float*)d_in[4];
  const float* Pw    = (const float*)d_in[5];
  const float* Aw    = (const float*)d_in[6];
  const float* gamma = (const float*)d_in[7];
  const float* beta  = (const float*)d_in[8];
  const float* alpha = (const float*)d_in[9];
  float* out = (float*)d_out;

  char* w = (char*)d_ws;
  u16*   Xt_x   = (u16*)(w);                 // 8192x2048 bf16 = 33.55 MB
  u16*   XtA    = (u16*)(w + 33554432);      // 33.55 MB
  u16*   XtF    = (u16*)(w + 67108864);      // 33.55 MB
  u16*   comb   = (u16*)(w + 100663296);     // 131072x256 bf16 [Xa|Xf] = 67.1 MB
  u16*   priorS = (u16*)(w + 167772160);     // 8.39 MB
  u16*   attnb  = (u16*)(w + 176160768);     // 8.39 MB
  u16*   e3b    = (u16*)(w + 185597952);     // 256 KB
  u16*   fb     = (u16*)(w + 186122240);     // 256 KB
  u16*   btc    = (u16*)(w + 186654720);     // 2x128x256 bf16 = 131 KB
  // aliased (lifetime-disjoint) regions:
  float* logits1 = (float*)(w + 33554432);   // XtA region: dead until after topp1
  float* logits2 = (float*)(w);              // Xt_x region: dead after step-1 gemm32
  u16*   d1      = (u16*)(w);                // Xt_x region: dead after topp2
  u16*   d2      = (u16*)(w + 33554432);     // XtA region: dead after step-2 gemm32
  (void)in_sizes; (void)n_in; (void)ws_size;

  static bool attr_done = false;
  if (!attr_done) {
    hipFuncSetAttribute(reinterpret_cast<const void*>(gemm32<1>),
                        hipFuncAttributeMaxDynamicSharedMemorySize, 131072);
    hipFuncSetAttribute(reinterpret_cast<const void*>(gemm32<2>),
                        hipFuncAttributeMaxDynamicSharedMemorySize, 131072);
    attr_done = true;
  }

  // merged prologue: priornorm | convx | convw
  prep_k<<<6400, 256, 0, stream>>>(prior, (ushort4*)priorS, x, Xt_x, Pw, Aw, btc);

  // step 1 attention (pooled+epre fused)
  pooled_epre_k<0><<<2048, 256, 0, stream>>>(x, nullptr, W1, W2, W3, e3b, fb);
  gemm_bt<3> <<<dim3(16, 16), 256, 16384, stream>>>(fb, e3b, 2048, 2048, 64,
                                                    logits1, nullptr, 0, 0);
  topp_k     <<<512, 256, 0, stream>>>(logits1, attnb);

  // Xa1 = attn1 @ x ; Xf1 = Rf @ x — pair-fused one dispatch (shared B=Xt_x)
  gemm32<1><<<dim3(32, 16), 512, 131072, stream>>>(attnb, priorS, Xt_x, Xt_x,
                                                   8192, 2048, comb, 256,
                                                   XtA, XtF, 2048);

  // step 2 attention (pooled over Xa1 from comb); logits2 aliases dead Xt_x
  pooled_epre_k<1><<<2048, 256, 0, stream>>>(nullptr, comb, W1, W2, W3, e3b, fb);
  gemm_bt<3> <<<dim3(16, 16), 256, 16384, stream>>>(fb, e3b, 2048, 2048, 64,
                                                    logits2, nullptr, 0, 0);
  topp_k     <<<512, 256, 0, stream>>>(logits2, attnb);

  // d1 = Xa1 @ Aw1^T + Xf1 @ Pw1^T  (bf16, into dead Xt_x region; no RMW)
  gemm_bt<2><<<dim3(1, 1024), 256, 34816, stream>>>(comb, btc, 131072, 128, 256,
                                                    nullptr, d1, 128, 0);

  // Xa2 = attn2 @ Xa1 ; Xf2 = Rf @ Xf1 — pair-fused one dispatch
  gemm32<2><<<dim3(32, 16), 512, 131072, stream>>>(attnb, priorS, XtA, XtF,
                                                   8192, 2048, comb, 256,
                                                   nullptr, nullptr, 0);

  // d2 = Xa2 @ Aw2^T + Xf2 @ Pw2^T  (bf16, into dead XtA region)
  gemm_bt<2><<<dim3(1, 1024), 256, 34816, stream>>>(comb, btc + 32768, 131072, 128, 256,
                                                    nullptr, d2, 128, 0);

  ln_k<<<16384, 256, 0, stream>>>(x, d1, d2, out, gamma, beta, alpha);
}

// Round 19
// 575.867 us; speedup vs baseline: 1.0246x; 1.0246x over previous
//
#include <hip/hip_runtime.h>

typedef unsigned short u16;
typedef __attribute__((ext_vector_type(8))) short short8;
typedef __attribute__((ext_vector_type(4))) float f32x4;

#define AS1 __attribute__((address_space(1)))
#define AS3 __attribute__((address_space(3)))

__device__ __forceinline__ void async_cp16(const void* g, void* l) {
  __builtin_amdgcn_global_load_lds((const AS1 unsigned int*)g, (AS3 unsigned int*)l, 16, 0, 0);
}

__device__ __forceinline__ u16 f2bf(float f) {
  union { float f; unsigned u; } v; v.f = f;
  unsigned r = v.u + 0x7fffu + ((v.u >> 16) & 1u);
  return (u16)(r >> 16);
}
__device__ __forceinline__ float bf2f(u16 h) {
  union { unsigned u; float f; } v; v.u = ((unsigned)h) << 16;
  return v.f;
}

// ---------------------------------------------------------------------------
// Big diffusion GEMM — FINAL (R17 config, measured best 580.2us total;
// gemm32 152-154us/dispatch ~900TF, MfmaUtil 37.5%): m201-style 8-phase
// pipeline. 256x256 tile, BK=64, 512 thr = 8 waves (2Mx4N), 16x16x32 bf16
// MFMA, wave tile 128x64, acc[8][4]. Per K-tile: 4 quadrant phases of 16
// MFMA, snake (0,0)(0,1)(1,1)(1,0); per-phase LDS reads 12/4/8/0; reads
// FIRST, then one half-tile stage, then MFMA, ONE barrier per phase
// (A/B-verified: ST-before-reads −25%, double-barrier interior −7%).
// Counted vmcnt(4) at K-tile boundaries only (never drain-0 mid-loop).
// LDS 128KB = 2 dbuf x {A,B} x 2 halves x 2 K-panels [128][32] u16 (64B row
// stride, 2-bit chunk XOR involution on write-source and read).
// Pair-fused: by>>3 selects attn vs prior path.
// MODE 1: packed Crow + transposed Ct;  MODE 2: packed Crow only.
// ---------------------------------------------------------------------------
template<int MODE>
__global__ __launch_bounds__(512, 2) void gemm32(
    const u16* __restrict__ Aa, const u16* __restrict__ Ap,
    const u16* __restrict__ Ba, const u16* __restrict__ Bp,
    int N, int K,
    u16* __restrict__ Crow, int crow_ld,
    u16* __restrict__ Cta, u16* __restrict__ Ctp, int ct_ld)
{
  extern __shared__ u16 smem[];   // 65536 u16 = 128KB
  const int tid  = threadIdx.x;
  const int lane = tid & 63;
  const int w    = tid >> 6;             // 0..7
  const int half2 = blockIdx.y >> 3;     // 0: attn-path, 1: prior-path
  const int m0 = (blockIdx.y & 7) * 256;
  const int n0 = blockIdx.x * 256;
  const u16* A = half2 ? Ap : Aa;
  const u16* B = half2 ? Bp : Ba;
  const int coloff = half2 * 128;
  const int wm2 = w >> 2;                // 0..1 : M rows wm2*128..+127
  const int wn4 = w & 3;                 // 0..3 : N cols wn4*64..+63
  const int nh  = wn4 >> 1;              // B half
  const int nsub = (wn4 & 1) * 64;       // row base within B half
  const int ml = lane & 15;
  const int qd = lane >> 4;
  const int qs = (qd ^ ((ml >> 1) & 3)) * 8;   // swizzled read chunk (u16)

  f32x4 acc[8][4];
  const f32x4 zero = {0.f, 0.f, 0.f, 0.f};
#pragma unroll
  for (int i = 0; i < 8; i++)
#pragma unroll
    for (int j = 0; j < 4; j++) acc[i][j] = zero;

  const int sr  = lane >> 2;
  const int gch = ((lane & 3) ^ ((lane >> 3) & 3)) * 8;

#define ST_A(tt, hh) do {                                                     \
    u16* d0_ = smem + ((tt) & 1) * 32768 + ((hh) * 2 + 0) * 4096 + w * 512;   \
    u16* d1_ = smem + ((tt) & 1) * 32768 + ((hh) * 2 + 1) * 4096 + w * 512;   \
    const u16* s_ = A + (size_t)(m0 + (hh) * 128 + w * 16 + sr) * K + (tt) * 64 + gch; \
    async_cp16(s_, d0_); async_cp16(s_ + 32, d1_);                            \
  } while (0)
#define ST_B(tt, hhn) do {                                                    \
    u16* d0_ = smem + ((tt) & 1) * 32768 + 16384 + ((hhn) * 2 + 0) * 4096 + w * 512; \
    u16* d1_ = smem + ((tt) & 1) * 32768 + 16384 + ((hhn) * 2 + 1) * 4096 + w * 512; \
    const u16* s_ = B + (size_t)(n0 + (hhn) * 128 + w * 16 + sr) * K + (tt) * 64 + gch; \
    async_cp16(s_, d0_); async_cp16(s_ + 32, d1_);                            \
  } while (0)

  short8 Af[4][2], Bf[2][2][2];   // Af[i][ks]; Bf[nq][jf][ks]

#define READA(dbase, mq) do {                                                 \
    _Pragma("unroll")                                                         \
    for (int i_ = 0; i_ < 4; i_++)                                            \
      _Pragma("unroll")                                                       \
      for (int ks_ = 0; ks_ < 2; ks_++)                                       \
        Af[i_][ks_] = *(const short8*)(smem + (dbase) + (wm2 * 2 + ks_) * 4096 \
            + ((mq) * 64 + i_ * 16 + ml) * 32 + qs);                          \
  } while (0)
#define READB(dbase, nq) do {                                                 \
    _Pragma("unroll")                                                         \
    for (int jf_ = 0; jf_ < 2; jf_++)                                         \
      _Pragma("unroll")                                                       \
      for (int ks_ = 0; ks_ < 2; ks_++)                                       \
        Bf[nq][jf_][ks_] = *(const short8*)(smem + (dbase) + 16384            \
            + (nh * 2 + ks_) * 4096 + (nsub + (nq) * 32 + jf_ * 16 + ml) * 32 + qs); \
  } while (0)
#define MFMAQ(mq, nq) do {                                                    \
    __builtin_amdgcn_s_setprio(1);                                            \
    _Pragma("unroll")                                                         \
    for (int i_ = 0; i_ < 4; i_++)                                            \
      _Pragma("unroll")                                                       \
      for (int jf_ = 0; jf_ < 2; jf_++)                                       \
        _Pragma("unroll")                                                     \
        for (int ks_ = 0; ks_ < 2; ks_++)                                     \
          acc[(mq) * 4 + i_][(nq) * 2 + jf_] = __builtin_amdgcn_mfma_f32_16x16x32_bf16( \
              Af[i_][ks_], Bf[nq][jf_][ks_], acc[(mq) * 4 + i_][(nq) * 2 + jf_], 0, 0, 0); \
    __builtin_amdgcn_s_setprio(0);                                            \
  } while (0)

  const int NTI = K >> 7;                // iterations; 2 K-tiles each
  ST_B(0, 0); ST_B(0, 1); ST_A(0, 0); ST_A(0, 1); ST_B(1, 0); ST_B(1, 1);
  asm volatile("s_waitcnt vmcnt(4)" ::: "memory");
  __builtin_amdgcn_s_barrier();

  for (int j = 0; j < NTI; ++j) {
    const int T = 2 * j;
    const bool st = (j + 1 < NTI);
    const int b0 = 0;
    const int b1 = 32768;

    // ---- ph0: T (0,0); stage A0(T+1)
    READA(b0, 0); READB(b0, 0);
    ST_A(T + 1, 0);
    MFMAQ(0, 0);
    __builtin_amdgcn_s_barrier();
    // ---- ph1: T (0,1); stage A1(T+1)
    READB(b0, 1);
    ST_A(T + 1, 1);
    MFMAQ(0, 1);
    __builtin_amdgcn_s_barrier();
    // ---- ph2: T (1,1); stage B0(T+2)
    READA(b0, 1);
    if (st) ST_B(T + 2, 0);
    MFMAQ(1, 1);
    __builtin_amdgcn_s_barrier();
    // ---- ph3: T (1,0); stage B1(T+2); boundary wait (counted)
    if (st) ST_B(T + 2, 1);
    MFMAQ(1, 0);
    if (st) { asm volatile("s_waitcnt vmcnt(4)" ::: "memory"); }
    else    { asm volatile("s_waitcnt vmcnt(0)" ::: "memory"); }
    __builtin_amdgcn_s_barrier();
    // ---- ph4: T+1 (0,0); stage A0(T+2)
    READA(b1, 0); READB(b1, 0);
    if (st) ST_A(T + 2, 0);
    MFMAQ(0, 0);
    __builtin_amdgcn_s_barrier();
    // ---- ph5: T+1 (0,1); stage A1(T+2)
    READB(b1, 1);
    if (st) ST_A(T + 2, 1);
    MFMAQ(0, 1);
    __builtin_amdgcn_s_barrier();
    // ---- ph6: T+1 (1,1); stage B0(T+3)
    READA(b1, 1);
    if (st) ST_B(T + 3, 0);
    MFMAQ(1, 1);
    __builtin_amdgcn_s_barrier();
    // ---- ph7: T+1 (1,0); stage B1(T+3); boundary wait
    if (st) ST_B(T + 3, 1);
    MFMAQ(1, 0);
    if (st) { asm volatile("s_waitcnt vmcnt(4)" ::: "memory"); }
    else    { asm volatile("s_waitcnt vmcnt(0)" ::: "memory"); }
    __builtin_amdgcn_s_barrier();
  }
#undef ST_A
#undef ST_B
#undef READA
#undef READB
#undef MFMAQ

  // Epilogues. C/D (m89): M-row = base + qd*4 + r, N-col = base + ml.
  u16* T = smem;   // [64][264] bounce (loop exited via barrier, all LDS dead)

  // packed row-major: 4 passes of 64 M-rows
#pragma unroll
  for (int pr = 0; pr < 4; pr++) {
    if (wm2 == (pr >> 1)) {
      const int mq = pr & 1;
#pragma unroll
      for (int i = 0; i < 4; i++)
#pragma unroll
        for (int nj = 0; nj < 4; nj++)
#pragma unroll
          for (int r = 0; r < 4; r++)
            T[(i * 16 + qd * 4 + r) * 264 + wn4 * 64 + nj * 16 + ml] =
                f2bf(acc[mq * 4 + i][nj][r]);
    }
    __syncthreads();
    {
      const int row = tid >> 3, c8 = tid & 7;    // 64 rows x 8 chunks of 32 u16
      const size_t grow = (size_t)(m0 + pr * 64 + row);
      const size_t crow = grow * (size_t)(N >> 7) + (n0 >> 7) + (c8 >> 2);
      u16* dst = Crow + crow * (size_t)crow_ld + coloff + (c8 & 3) * 32;
      const u16* src = T + row * 264 + c8 * 32;
#pragma unroll
      for (int u = 0; u < 4; u++) ((float4*)dst)[u] = ((const float4*)src)[u];
    }
    __syncthreads();
  }

  if constexpr (MODE == 1) {
    u16* Ct = half2 ? Ctp : Cta;
    // transposed: Ct[n][m], 4 passes of 64 n-rows x 256 m-cols
#pragma unroll
    for (int p = 0; p < 4; p++) {
      if (wn4 == p) {
#pragma unroll
        for (int mi = 0; mi < 8; mi++)
#pragma unroll
          for (int nj = 0; nj < 4; nj++)
#pragma unroll
            for (int r = 0; r < 4; r++) {
              const int nloc = nj * 16 + ml;
              const int mcol = wm2 * 128 + (mi >> 2) * 64 + (mi & 3) * 16 + qd * 4 + r;
              T[nloc * 264 + mcol] = f2bf(acc[mi][nj][r]);
            }
      }
      __syncthreads();
      {
        const int row = tid >> 3, c8 = tid & 7;
        u16* dst = Ct + (size_t)(n0 + p * 64 + row) * ct_ld + m0 + c8 * 32;
        const u16* src = T + row * 264 + c8 * 32;
#pragma unroll
        for (int u = 0; u < 4; u++) ((float4*)dst)[u] = ((const float4*)src)[u];
      }
      __syncthreads();
    }
  }
}

// ---------------------------------------------------------------------------
// 16x16x32 GEMM (small shapes) — BK=32 body (A/B-verified vs BK=64: −13us).
// R9 chunk-XOR swizzle: store chunk c of row r at c ^ ((r>>1)&3)
// (global-source side, LDS linear); read chunk qd ^ ((ml>>1)&3).
// MODE 2: bf16 packed row-major; MODE 3: f32 plain.
// ---------------------------------------------------------------------------
template<int MODE>
__global__ __launch_bounds__(256) void gemm_bt(
    const u16* __restrict__ A, const u16* __restrict__ B,
    int M, int N, int K,
    float* __restrict__ Cf,
    u16* __restrict__ Crow, int crow_ld, int crow_coloff)
{
  extern __shared__ char smemc[];
  u16* sA = (u16*)smemc;
  u16* sB = (u16*)(smemc + 8192);
  const int tid  = threadIdx.x;
  const int lane = tid & 63;
  const int wid  = tid >> 6;
  const int m0 = blockIdx.y * 128;
  const int n0 = blockIdx.x * 128;
  const int wm = (wid >> 1) * 64;
  const int wn = (wid & 1) * 64;
  const int ml = lane & 15;
  const int qd = lane >> 4;
  const int qs = (qd ^ ((ml >> 1) & 3)) * 8;   // swizzled read chunk (u16)

  f32x4 acc[4][4];
  const f32x4 zero = {0.f, 0.f, 0.f, 0.f};
#pragma unroll
  for (int i = 0; i < 4; i++)
#pragma unroll
    for (int j = 0; j < 4; j++) acc[i][j] = zero;

  const int r4 = tid >> 2;
  const int pq = (r4 >> 1) & 3;                // staging row swizzle key
  const int c4 = ((tid & 3) ^ pq) * 8;         // swizzled global source chunk
  const u16* gA0 = A + (size_t)(m0 + r4) * K + c4;
  const u16* gA1 = A + (size_t)(m0 + 64 + r4) * K + c4;
  const u16* gB0 = B + (size_t)(n0 + r4) * K + c4;
  const u16* gB1 = B + (size_t)(n0 + 64 + r4) * K + c4;
  u16* lA0 = sA + wid * 512;
  u16* lA1 = sA + 2048 + wid * 512;
  u16* lB0 = sB + wid * 512;
  u16* lB1 = sB + 2048 + wid * 512;

  for (int k0 = 0; k0 < K; k0 += 32) {
    async_cp16(gA0 + k0, lA0);
    async_cp16(gA1 + k0, lA1);
    async_cp16(gB0 + k0, lB0);
    async_cp16(gB1 + k0, lB1);
    __syncthreads();
    short8 af[4], bfr[4];
#pragma unroll
    for (int i = 0; i < 4; i++)
      af[i] = *(const short8*)(sA + (wm + i * 16 + ml) * 32 + qs);
#pragma unroll
    for (int j = 0; j < 4; j++)
      bfr[j] = *(const short8*)(sB + (wn + j * 16 + ml) * 32 + qs);
#pragma unroll
    for (int i = 0; i < 4; i++)
#pragma unroll
      for (int j = 0; j < 4; j++)
        acc[i][j] = __builtin_amdgcn_mfma_f32_16x16x32_bf16(af[i], bfr[j], acc[i][j], 0, 0, 0);
    __syncthreads();
  }

  if constexpr (MODE == 3) {
#pragma unroll
    for (int i = 0; i < 4; i++) {
      const int mr = m0 + wm + i * 16 + qd * 4;
#pragma unroll
      for (int j = 0; j < 4; j++) {
        const int nc = n0 + wn + j * 16 + ml;
        float* p = Cf + (size_t)mr * N + nc;
#pragma unroll
        for (int r = 0; r < 4; r++) p[(size_t)r * N] = acc[i][j][r];
      }
    }
  } else {
    u16* T = (u16*)smemc;  // [128][136]
#pragma unroll
    for (int i = 0; i < 4; i++)
#pragma unroll
      for (int j = 0; j < 4; j++)
#pragma unroll
        for (int r = 0; r < 4; r++)
          T[(wm + i * 16 + qd * 4 + r) * 136 + wn + j * 16 + ml] = f2bf(acc[i][j][r]);
    __syncthreads();
    const int row = tid >> 1, halfr = tid & 1;
    const size_t crow = (size_t)(m0 + row) * (N >> 7) + (n0 >> 7);
    u16* dst = Crow + crow * (size_t)crow_ld + crow_coloff + halfr * 64;
    const u16* src = T + row * 136 + halfr * 64;
#pragma unroll
    for (int u = 0; u < 8; u++) ((float4*)dst)[u] = ((const float4*)src)[u];
  }
}

// ---------------------------------------------------------------------------
// prep_k: merged prologue (one dispatch, block-range branch):
//  [0,2048) priornorm | [2048,6144) convx | [6144,6400) convw
// ---------------------------------------------------------------------------
__global__ __launch_bounds__(256) void prep_k(
    const float* __restrict__ prior, ushort4* __restrict__ priorS,
    const float* __restrict__ x, u16* __restrict__ xt,
    const float* __restrict__ pw, const float* __restrict__ aw,
    u16* __restrict__ btc)
{
  const int bid = blockIdx.x;
  const int t = threadIdx.x;
  if (bid < 2048) {
    __shared__ float red[256];
    const int i = bid;
    const float* p = prior + (size_t)i * 2048;
    float s = 0.f;
    for (int j = t; j < 2048; j += 256) s += p[j];
    red[t] = s; __syncthreads();
    for (int o = 128; o; o >>= 1) { if (t < o) red[t] += red[t + o]; __syncthreads(); }
    const float inv = 1.0f / red[0];
    const float4* pv = (const float4*)p;
    ushort4* dv = priorS + (size_t)i * 512;
#pragma unroll
    for (int j = t; j < 512; j += 256) {
      const float4 v = pv[j];
      ushort4 o;
      o.x = f2bf(v.x * inv); o.y = f2bf(v.y * inv); o.z = f2bf(v.z * inv); o.w = f2bf(v.w * inv);
      dv[j] = o;
    }
  } else if (bid < 6144) {
    __shared__ float S[64][65];
    const int b2 = bid - 2048;
    const int n0 = (b2 & 127) * 64;
    const int j0 = (b2 >> 7) * 64;
    const int rr = t >> 4, cxc = (t & 15) * 4;
#pragma unroll
    for (int p = 0; p < 4; p++) {
      const float4 v = *(const float4*)(x + (size_t)(j0 + rr + p * 16) * 8192 + n0 + cxc);
      S[rr + p * 16][cxc + 0] = v.x; S[rr + p * 16][cxc + 1] = v.y;
      S[rr + p * 16][cxc + 2] = v.z; S[rr + p * 16][cxc + 3] = v.w;
    }
    __syncthreads();
    const int nl = t >> 2, ch = (t & 3) * 16;
    alignas(16) u16 tmp[16];
#pragma unroll
    for (int u = 0; u < 16; u++) tmp[u] = f2bf(S[ch + u][nl]);
    float4* dst = (float4*)(xt + (size_t)(n0 + nl) * 2048 + j0 + ch);
    dst[0] = ((const float4*)tmp)[0];
    dst[1] = ((const float4*)tmp)[1];
  } else {
    const int idx = (bid - 6144) * 256 + t;
    const int k = idx & 255, d = (idx >> 8) & 127, s = idx >> 15;
    const float v = (k < 128) ? aw[(s * 128 + d) * 128 + k] : pw[(s * 128 + d) * 128 + (k - 128)];
    btc[idx] = f2bf(v);
  }
}

// ---------------------------------------------------------------------------
// pooled_epre_k<SRC>: fused pooled + epre
// ---------------------------------------------------------------------------
template<int SRC>
__global__ __launch_bounds__(256) void pooled_epre_k(
    const float* __restrict__ xf, const u16* __restrict__ comb,
    const float* __restrict__ W1, const float* __restrict__ W2,
    const float* __restrict__ W3,
    u16* __restrict__ e3b, u16* __restrict__ fb)
{
  __shared__ float red[256];
  __shared__ float pr[128];
  __shared__ float e1s[64];
  const int i = blockIdx.x, t = threadIdx.x;
  const int c = t & 127, h = t >> 7;
  float s = 0.f;
  if constexpr (SRC == 0) {
    const float* base = xf + (size_t)i * 8192 + c;
    for (int k = h * 32; k < h * 32 + 32; k++) s += base[(size_t)k * 128];
  } else {
    const u16* base = comb + (size_t)i * 64 * 256 + c;
    for (int k = h * 32; k < h * 32 + 32; k++) s += bf2f(base[(size_t)k * 256]);
  }
  red[t] = s; __syncthreads();
  if (t < 128) pr[t] = (red[t] + red[t + 128]) * (1.f / 64.f);
  __syncthreads();
  if (t < 128) {
    const float* Wm = (t < 64) ? W1 : W3;
    const int d = t & 63;
    float sv = 0.f;
    for (int cc = 0; cc < 128; cc++) sv += pr[cc] * Wm[d * 128 + cc];
    if (t < 64) e1s[d] = sv;
    else        e3b[i * 64 + d] = f2bf(sv);
  }
  __syncthreads();
  if (t < 64) {
    float sf = 0.f;
    for (int dd = 0; dd < 64; dd++) sf += e1s[dd] * W2[t * 64 + dd];
    fb[i * 64 + t] = f2bf(sf);
  }
}

__device__ __forceinline__ float waveRedSum(float v) {
#pragma unroll
  for (int o = 1; o < 64; o <<= 1) v += __shfl_xor(v, o);
  return __shfl(v, 0);
}
__device__ __forceinline__ float waveRedMax(float v) {
#pragma unroll
  for (int o = 1; o < 64; o <<= 1) v = fmaxf(v, __shfl_xor(v, o));
  return __shfl(v, 0);
}

__global__ __launch_bounds__(256) void topp_k(const float* __restrict__ logits,
                                              u16* __restrict__ attnb) {
  const int w = threadIdx.x >> 6, l = threadIdx.x & 63;
  const int i = blockIdx.x * 4 + w;
  const float4* row = (const float4*)(logits + (size_t)i * 2048);
  float E[32];
  float mx = -1e30f;
#pragma unroll
  for (int k = 0; k < 8; k++) {
    const float4 v = row[k * 64 + l];
    E[k * 4 + 0] = v.x; E[k * 4 + 1] = v.y; E[k * 4 + 2] = v.z; E[k * 4 + 3] = v.w;
    mx = fmaxf(fmaxf(mx, fmaxf(v.x, v.y)), fmaxf(v.z, v.w));
  }
  mx = waveRedMax(mx);
  float S = 0.f;
#pragma unroll
  for (int u = 0; u < 32; u++) { E[u] = __expf(E[u] - mx); S += E[u]; }
  S = waveRedSum(S);
  const float target = 0.9f * S;
  float lo = 0.f, hi = 1.f;
  for (int it = 0; it < 32; ++it) {
    const float mid = 0.5f * (lo + hi);
    float g = 0.f;
#pragma unroll
    for (int u = 0; u < 32; u++) g += (E[u] > mid) ? E[u] : 0.f;
    g = waveRedSum(g);
    const bool below = (g < target);
    hi = below ? mid : hi;
    lo = below ? lo : mid;
  }
  float Sk = 0.f;
#pragma unroll
  for (int u = 0; u < 32; u++) Sk += (E[u] > lo) ? E[u] : 0.f;
  Sk = waveRedSum(Sk);
  const float inv = 1.f / Sk;
  u16* dst = attnb + (size_t)i * 2048;
#pragma unroll
  for (int k = 0; k < 8; k++) {
    ushort4 o;
    o.x = f2bf(E[k * 4 + 0] > lo ? E[k * 4 + 0] * inv : 0.f);
    o.y = f2bf(E[k * 4 + 1] > lo ? E[k * 4 + 1] * inv : 0.f);
    o.z = f2bf(E[k * 4 + 2] > lo ? E[k * 4 + 2] * inv : 0.f);
    o.w = f2bf(E[k * 4 + 3] > lo ? E[k * 4 + 3] * inv : 0.f);
    *(ushort4*)(dst + k * 256 + l * 4) = o;
  }
}

// out = LN(x + gate*(d1+d2))*gamma + beta  (deltas stored bf16)
__global__ void ln_k(const float* __restrict__ x,
                     const u16* __restrict__ d1, const u16* __restrict__ d2,
                     float* __restrict__ out,
                     const float* __restrict__ gamma, const float* __restrict__ beta,
                     const float* __restrict__ alpha) {
  const int wid = threadIdx.x >> 6, lane = threadIdx.x & 63;
  const float gate = 1.f / (1.f + expf(-alpha[0]));
  const float2 g = ((const float2*)gamma)[lane];
  const float2 b = ((const float2*)beta)[lane];
#pragma unroll
  for (int rr = 0; rr < 2; ++rr) {
    const size_t row = (size_t)blockIdx.x * 8 + wid * 2 + rr;
    const float2 xv = ((const float2*)(x + row * 128))[lane];
    const ushort2 r1 = ((const ushort2*)(d1 + row * 128))[lane];
    const ushort2 r2 = ((const ushort2*)(d2 + row * 128))[lane];
    const float h0 = xv.x + gate * (bf2f(r1.x) + bf2f(r2.x));
    const float h1 = xv.y + gate * (bf2f(r1.y) + bf2f(r2.y));
    float s = h0 + h1;
#pragma unroll
    for (int o = 32; o; o >>= 1) s += __shfl_down(s, o);
    const float mu = __shfl(s, 0) * (1.f / 128.f);
    const float d0 = h0 - mu, dd1 = h1 - mu;
    float vs = d0 * d0 + dd1 * dd1;
#pragma unroll
    for (int o = 32; o; o >>= 1) vs += __shfl_down(vs, o);
    const float rstd = rsqrtf(__shfl(vs, 0) * (1.f / 128.f) + 1e-5f);
    float2* op = (float2*)(out + row * 128);
    float2 ov;
    ov.x = d0 * rstd * g.x + b.x;
    ov.y = dd1 * rstd * g.y + b.y;
    op[lane] = ov;
  }
}

// ---------------------------------------------------------------------------
extern "C" void kernel_launch(void* const* d_in, const int* in_sizes, int n_in,
                              void* d_out, int out_size, void* d_ws, size_t ws_size,
                              hipStream_t stream) {
  const float* x     = (const float*)d_in[0];
  const float* prior = (const float*)d_in[1];
  const float* W1    = (const float*)d_in[2];
  const float* W2    = (const float*)d_in[3];
  const float* W3    = (const float*)d_in[4];
  const float* Pw    = (const float*)d_in[5];
  const float* Aw    = (const float*)d_in[6];
  const float* gamma = (const float*)d_in[7];
  const float* beta  = (const float*)d_in[8];
  const float* alpha = (const float*)d_in[9];
  float* out = (float*)d_out;

  char* w = (char*)d_ws;
  u16*   Xt_x   = (u16*)(w);                 // 8192x2048 bf16 = 33.55 MB
  u16*   XtA    = (u16*)(w + 33554432);      // 33.55 MB
  u16*   XtF    = (u16*)(w + 67108864);      // 33.55 MB
  u16*   comb   = (u16*)(w + 100663296);     // 131072x256 bf16 [Xa|Xf] = 67.1 MB
  u16*   priorS = (u16*)(w + 167772160);     // 8.39 MB
  u16*   attnb  = (u16*)(w + 176160768);     // 8.39 MB
  u16*   e3b    = (u16*)(w + 185597952);     // 256 KB
  u16*   fb     = (u16*)(w + 186122240);     // 256 KB
  u16*   btc    = (u16*)(w + 186654720);     // 2x128x256 bf16 = 131 KB
  // aliased (lifetime-disjoint) regions:
  float* logits1 = (float*)(w + 33554432);   // XtA region: dead until after topp1
  float* logits2 = (float*)(w);              // Xt_x region: dead after step-1 gemm32
  u16*   d1      = (u16*)(w);                // Xt_x region: dead after topp2
  u16*   d2      = (u16*)(w + 33554432);     // XtA region: dead after step-2 gemm32
  (void)in_sizes; (void)n_in; (void)ws_size;

  static bool attr_done = false;
  if (!attr_done) {
    hipFuncSetAttribute(reinterpret_cast<const void*>(gemm32<1>),
                        hipFuncAttributeMaxDynamicSharedMemorySize, 131072);
    hipFuncSetAttribute(reinterpret_cast<const void*>(gemm32<2>),
                        hipFuncAttributeMaxDynamicSharedMemorySize, 131072);
    attr_done = true;
  }

  // merged prologue: priornorm | convx | convw
  prep_k<<<6400, 256, 0, stream>>>(prior, (ushort4*)priorS, x, Xt_x, Pw, Aw, btc);

  // step 1 attention (pooled+epre fused)
  pooled_epre_k<0><<<2048, 256, 0, stream>>>(x, nullptr, W1, W2, W3, e3b, fb);
  gemm_bt<3> <<<dim3(16, 16), 256, 16384, stream>>>(fb, e3b, 2048, 2048, 64,
                                                    logits1, nullptr, 0, 0);
  topp_k     <<<512, 256, 0, stream>>>(logits1, attnb);

  // Xa1 = attn1 @ x ; Xf1 = Rf @ x — pair-fused one dispatch (shared B=Xt_x)
  gemm32<1><<<dim3(32, 16), 512, 131072, stream>>>(attnb, priorS, Xt_x, Xt_x,
                                                   8192, 2048, comb, 256,
                                                   XtA, XtF, 2048);

  // step 2 attention (pooled over Xa1 from comb); logits2 aliases dead Xt_x
  pooled_epre_k<1><<<2048, 256, 0, stream>>>(nullptr, comb, W1, W2, W3, e3b, fb);
  gemm_bt<3> <<<dim3(16, 16), 256, 16384, stream>>>(fb, e3b, 2048, 2048, 64,
                                                    logits2, nullptr, 0, 0);
  topp_k     <<<512, 256, 0, stream>>>(logits2, attnb);

  // d1 = Xa1 @ Aw1^T + Xf1 @ Pw1^T  (bf16, into dead Xt_x region; no RMW)
  gemm_bt<2><<<dim3(1, 1024), 256, 34816, stream>>>(comb, btc, 131072, 128, 256,
                                                    nullptr, d1, 128, 0);

  // Xa2 = attn2 @ Xa1 ; Xf2 = Rf @ Xf1 — pair-fused one dispatch
  gemm32<2><<<dim3(32, 16), 512, 131072, stream>>>(attnb, priorS, XtA, XtF,
                                                   8192, 2048, comb, 256,
                                                   nullptr, nullptr, 0);

  // d2 = Xa2 @ Aw2^T + Xf2 @ Pw2^T  (bf16, into dead XtA region)
  gemm_bt<2><<<dim3(1, 1024), 256, 34816, stream>>>(comb, btc + 32768, 131072, 128, 256,
                                                    nullptr, d2, 128, 0);

  ln_k<<<16384, 256, 0, stream>>>(x, d1, d2, out, gamma, beta, alpha);
}